// Round 3
// baseline (470.574 us; speedup 1.0000x reference)
//
#include <hip/hip_runtime.h>
#include <cstdint>
#include <cstddef>

#define DIM 16384
#define BSIZE 32
#define MAX_STEPS 9
#define TPB1 256
#define JSUB 256
#define TPB3 1024
#define KV 4  // float4 vectors per thread in K3 (4*4*1024 = 16384)

typedef float f32x4 __attribute__((ext_vector_type(4)));

// ---------------- K0: tiled transpose x [B][D] -> xT [D][B] ----------------
__global__ __launch_bounds__(256) void k_xpose(const float* __restrict__ x,
                                               float* __restrict__ xT) {
    __shared__ float tile[64][33];
    const int j0 = blockIdx.x * 64;
    const int t = threadIdx.x;
    {
        int col = t & 63;
        int r0 = t >> 6;  // 0..3
#pragma unroll
        for (int r = 0; r < 8; ++r) {
            int row = r * 4 + r0;  // 0..31, coalesced 256B per 64-lane group
            tile[col][row] = x[(size_t)row * DIM + j0 + col];
        }
    }
    __syncthreads();
    {
        int b = t & 31;
        int q0 = t >> 5;  // 0..7
#pragma unroll
        for (int r = 0; r < 8; ++r) {
            int jj = r * 8 + q0;  // 0..63; block writes 8KB contiguous
            xT[(size_t)(j0 + jj) * BSIZE + b] = tile[jj][b];
        }
    }
}

// ------- K1: partial[slot][b][c] = sum_{j in slot} x[b][j] * W[j][c] -------
// 256 threads x 4 cols = 1024 cols/block. grid=(DIM/1024, nslots).
// Per jj: 1 global dwordx4 (W) + 8 ds_read_b128 (x bcast) + 128 FMA -> 1:16 LDS:FMA.
__global__ __launch_bounds__(TPB1, 2) void k_matmul(
        const float* __restrict__ W, const float* __restrict__ xT,
        float* __restrict__ partial, int jb) {
    __shared__ float ldsx[JSUB * BSIZE];  // 32 KB
    const int t = threadIdx.x;
    const int c0 = (blockIdx.x * TPB1 + t) * 4;
    const int j0 = blockIdx.y * jb;

    f32x4 acc[BSIZE];
#pragma unroll
    for (int b = 0; b < BSIZE; ++b) acc[b] = (f32x4)(0.f);

    for (int js = 0; js < jb; js += JSUB) {
        __syncthreads();  // protect previous chunk's LDS reads
        {
            const f32x4* src = (const f32x4*)(xT + (size_t)(j0 + js) * BSIZE);
            f32x4* dst = (f32x4*)ldsx;
#pragma unroll
            for (int q = 0; q < (JSUB * BSIZE / 4 / TPB1); ++q)  // 8
                dst[t + q * TPB1] = src[t + q * TPB1];
        }
        __syncthreads();
        const float* wp = W + (size_t)(j0 + js) * DIM + c0;
#pragma unroll 2
        for (int jj = 0; jj < JSUB; ++jj) {
            f32x4 w = __builtin_nontemporal_load((const f32x4*)wp);  // 1KB/wave, nt
            wp += DIM;
            const f32x4* xr = (const f32x4*)(ldsx + jj * BSIZE);  // uniform -> bcast
#pragma unroll
            for (int q = 0; q < 8; ++q) {
                f32x4 xv = xr[q];
                float xs[4] = {xv.x, xv.y, xv.z, xv.w};
#pragma unroll
                for (int e = 0; e < 4; ++e) {
                    int b = q * 4 + e;
                    acc[b].x = fmaf(w.x, xs[e], acc[b].x);
                    acc[b].y = fmaf(w.y, xs[e], acc[b].y);
                    acc[b].z = fmaf(w.z, xs[e], acc[b].z);
                    acc[b].w = fmaf(w.w, xs[e], acc[b].w);
                }
            }
        }
    }
    f32x4* pp = (f32x4*)(partial + (size_t)blockIdx.y * BSIZE * DIM);
    const int c4 = c0 >> 2;
#pragma unroll
    for (int b = 0; b < BSIZE; ++b) pp[(size_t)b * (DIM / 4) + c4] = acc[b];
}

// ------- K2: h0 = sum_slots partial + bias (float4) -------
__global__ __launch_bounds__(256) void k_reduce(const float* __restrict__ partial,
                                                const float* __restrict__ bias,
                                                float* __restrict__ h0, int nslots) {
    int i4 = blockIdx.x * 256 + threadIdx.x;  // over B*DIM/4
    int c4 = i4 & (DIM / 4 - 1);
    const f32x4* p = (const f32x4*)partial;
    f32x4 s = ((const f32x4*)bias)[c4];
    for (int sl = 0; sl < nslots; ++sl)
        s += p[(size_t)sl * (BSIZE * DIM / 4) + i4];
    ((f32x4*)h0)[i4] = s;
}

// ---------------- K3 block-wide reductions (1024 thr = 16 waves) ----------------
__device__ __forceinline__ float block_reduce_max(float v, float* red) {
#pragma unroll
    for (int off = 1; off < 64; off <<= 1) v = fmaxf(v, __shfl_xor(v, off));
    int lane = threadIdx.x & 63, wv = threadIdx.x >> 6;
    if (lane == 0) red[wv] = v;
    __syncthreads();
    if (threadIdx.x == 0) {
        float m = red[0];
#pragma unroll
        for (int w = 1; w < TPB3 / 64; ++w) m = fmaxf(m, red[w]);
        red[0] = m;
    }
    __syncthreads();
    float r = red[0];
    __syncthreads();
    return r;
}

__device__ __forceinline__ float block_reduce_sum(float v, float* red) {
#pragma unroll
    for (int off = 1; off < 64; off <<= 1) v += __shfl_xor(v, off);
    int lane = threadIdx.x & 63, wv = threadIdx.x >> 6;
    if (lane == 0) red[wv] = v;
    __syncthreads();
    if (threadIdx.x == 0) {
        float s = red[0];
#pragma unroll
        for (int w = 1; w < TPB3 / 64; ++w) s += red[w];
        red[0] = s;
    }
    __syncthreads();
    float r = red[0];
    __syncthreads();
    return r;
}

__device__ __forceinline__ int block_argmax(float v, int idx, float* redf, int* redi) {
#pragma unroll
    for (int off = 1; off < 64; off <<= 1) {
        float ov = __shfl_xor(v, off);
        int oi = __shfl_xor(idx, off);
        if (ov > v || (ov == v && oi < idx)) { v = ov; idx = oi; }
    }
    int lane = threadIdx.x & 63, wv = threadIdx.x >> 6;
    if (lane == 0) { redf[wv] = v; redi[wv] = idx; }
    __syncthreads();
    if (threadIdx.x == 0) {
        float bv = redf[0]; int bi = redi[0];
#pragma unroll
        for (int w = 1; w < TPB3 / 64; ++w) {
            float ov = redf[w]; int oi = redi[w];
            if (ov > bv || (ov == bv && oi < bi)) { bv = ov; bi = oi; }
        }
        redi[0] = bi;
    }
    __syncthreads();
    int r = redi[0];
    __syncthreads();
    return r;
}

// ------- K3: per-row sampler, one block per batch row, h/sg in registers -------
__global__ __launch_bounds__(TPB3) void k_sample(
        const float* __restrict__ x, const float* __restrict__ W,
        const float* __restrict__ h0, const float* __restrict__ gumbel,
        const float* __restrict__ au, const int* __restrict__ radius,
        float* __restrict__ out) {
    __shared__ float redf[TPB3 / 64];
    __shared__ int   redi[TPB3 / 64];
    __shared__ float s_delta;
    const int b = blockIdx.x;
    const int t = threadIdx.x;

    const f32x4* h0v = (const f32x4*)(h0 + (size_t)b * DIM);
    const f32x4* xin = (const f32x4*)(x + (size_t)b * DIM);

    f32x4 h[KV], sg[KV];
#pragma unroll
    for (int v = 0; v < KV; ++v) {
        h[v] = h0v[t + v * TPB3];
        f32x4 xx = xin[t + v * TPB3];
        sg[v] = (f32x4)(1.0f) - 2.0f * xx;  // exactly +/-1
    }

    // Zx = logsumexp(sg*h*0.5)
    float lmax = -INFINITY;
#pragma unroll
    for (int v = 0; v < KV; ++v) {
        f32x4 l = sg[v] * h[v] * 0.5f;
        lmax = fmaxf(lmax, fmaxf(fmaxf(l.x, l.y), fmaxf(l.z, l.w)));
    }
    float m = block_reduce_max(lmax, redf);
    float lsum = 0.f;
#pragma unroll
    for (int v = 0; v < KV; ++v) {
        f32x4 l = sg[v] * h[v] * 0.5f;
        lsum += expf(l.x - m) + expf(l.y - m) + expf(l.z - m) + expf(l.w - m);
    }
    float S = block_reduce_sum(lsum, redf);
    float Zx = logf(S) + m;

    const int rad = radius[b];  // in [1, 9]; masked steps are no-ops
    for (int st = 0; st < rad; ++st) {
        const f32x4* g = (const f32x4*)(gumbel + ((size_t)st * BSIZE + b) * DIM);
        float best = -INFINITY; int bidx = 0;
#pragma unroll
        for (int v = 0; v < KV; ++v) {  // ascending c within thread; strict > keeps first
            f32x4 l = sg[v] * h[v] * 0.5f + g[t + v * TPB3];
            int base = (t + v * TPB3) * 4;
            if (l.x > best) { best = l.x; bidx = base + 0; }
            if (l.y > best) { best = l.y; bidx = base + 1; }
            if (l.z > best) { best = l.z; bidx = base + 2; }
            if (l.w > best) { best = l.w; bidx = base + 3; }
        }
        int idx = block_argmax(best, bidx, redf, redi);
        int c4 = idx >> 2;
        int towner = c4 & (TPB3 - 1);
        int vsel = c4 >> 10;
        int e = idx & 3;
        if (t == towner) {
            float dv = 0.f;
#pragma unroll
            for (int v = 0; v < KV; ++v) {
                if (v == vsel) {
                    f32x4 s4 = sg[v];
                    float d = (e == 0) ? s4.x : (e == 1) ? s4.y : (e == 2) ? s4.z : s4.w;
                    dv = d;
                    if (e == 0) s4.x = -s4.x;
                    else if (e == 1) s4.y = -s4.y;
                    else if (e == 2) s4.z = -s4.z;
                    else s4.w = -s4.w;
                    sg[v] = s4;
                }
            }
            s_delta = dv;  // delta = (1 - 2*x_old)
        }
        __syncthreads();
        float delta = s_delta;
        const f32x4* wr = (const f32x4*)(W + (size_t)idx * DIM);
#pragma unroll
        for (int v = 0; v < KV; ++v) {  // rank-1 update, coalesced float4
            f32x4 w = wr[t + v * TPB3];
            h[v].x = fmaf(delta, w.x, h[v].x);
            h[v].y = fmaf(delta, w.y, h[v].y);
            h[v].z = fmaf(delta, w.z, h[v].z);
            h[v].w = fmaf(delta, w.w, h[v].w);
        }
        __syncthreads();
    }

    // Zy
    lmax = -INFINITY;
#pragma unroll
    for (int v = 0; v < KV; ++v) {
        f32x4 l = sg[v] * h[v] * 0.5f;
        lmax = fmaxf(lmax, fmaxf(fmaxf(l.x, l.y), fmaxf(l.z, l.w)));
    }
    m = block_reduce_max(lmax, redf);
    lsum = 0.f;
#pragma unroll
    for (int v = 0; v < KV; ++v) {
        f32x4 l = sg[v] * h[v] * 0.5f;
        lsum += expf(l.x - m) + expf(l.y - m) + expf(l.z - m) + expf(l.w - m);
    }
    S = block_reduce_sum(lsum, redf);
    float Zy = logf(S) + m;

    int accepted = (expf(Zx - Zy) >= au[b]) ? 1 : 0;
    f32x4* ov = (f32x4*)(out + (size_t)b * DIM);
#pragma unroll
    for (int v = 0; v < KV; ++v) {
        f32x4 y;
        y.x = (sg[v].x < 0.f) ? 1.f : 0.f;
        y.y = (sg[v].y < 0.f) ? 1.f : 0.f;
        y.z = (sg[v].z < 0.f) ? 1.f : 0.f;
        y.w = (sg[v].w < 0.f) ? 1.f : 0.f;
        ov[t + v * TPB3] = accepted ? y : xin[t + v * TPB3];
    }
}

extern "C" void kernel_launch(void* const* d_in, const int* in_sizes, int n_in,
                              void* d_out, int out_size, void* d_ws, size_t ws_size,
                              hipStream_t stream) {
    (void)in_sizes; (void)n_in; (void)out_size;
    const float* x      = (const float*)d_in[0];
    const float* W      = (const float*)d_in[1];
    const float* bias   = (const float*)d_in[2];
    const float* gumbel = (const float*)d_in[3];
    const float* au     = (const float*)d_in[4];
    const int*   radius = (const int*)d_in[5];
    float* out = (float*)d_out;

    // ws layout: xT (2 MB) | partial (nslots * 2 MB) | h0 (2 MB)
    float* xT = (float*)d_ws;
    size_t xt_elems = (size_t)DIM * BSIZE;
    int nslots = 32;  // 16 x 32 = 512 blocks = 2 blocks/CU
    while (nslots > 1) {
        size_t need = (xt_elems + (size_t)(nslots + 1) * BSIZE * DIM) * sizeof(float);
        if (need <= ws_size) break;
        nslots >>= 1;
    }
    float* partial = xT + xt_elems;
    float* h0 = partial + (size_t)nslots * BSIZE * DIM;

    k_xpose<<<DIM / 64, 256, 0, stream>>>(x, xT);
    dim3 g1(DIM / (TPB1 * 4), nslots);
    k_matmul<<<g1, TPB1, 0, stream>>>(W, xT, partial, DIM / nslots);
    k_reduce<<<(BSIZE * DIM / 4) / 256, 256, 0, stream>>>(partial, bias, h0, nslots);
    k_sample<<<BSIZE, TPB3, 0, stream>>>(x, W, h0, gumbel, au, radius, out);
}

// Round 4
// 311.211 us; speedup vs baseline: 1.5121x; 1.5121x over previous
//
#include <hip/hip_runtime.h>
#include <cstdint>
#include <cstddef>

#define DIM 16384
#define BSIZE 32
#define MAX_STEPS 9
#define TPB1 256
#define TPB3 1024
#define KV 4  // float4 vectors per thread in K3 (4*4*1024 = 16384)

typedef float f32x4 __attribute__((ext_vector_type(4)));

__device__ __forceinline__ float rdlane(float v, int l) {
    return __int_as_float(__builtin_amdgcn_readlane(__float_as_int(v), l));
}

// ---------------- K0: tiled transpose x [B][D] -> xT [D][B] ----------------
__global__ __launch_bounds__(256) void k_xpose(const float* __restrict__ x,
                                               float* __restrict__ xT) {
    __shared__ float tile[64][33];
    const int j0 = blockIdx.x * 64;
    const int t = threadIdx.x;
    {
        int col = t & 63;
        int r0 = t >> 6;  // 0..3
#pragma unroll
        for (int r = 0; r < 8; ++r) {
            int row = r * 4 + r0;  // 0..31
            tile[col][row] = x[(size_t)row * DIM + j0 + col];
        }
    }
    __syncthreads();
    {
        int b = t & 31;
        int q0 = t >> 5;  // 0..7
#pragma unroll
        for (int r = 0; r < 8; ++r) {
            int jj = r * 8 + q0;  // 0..63
            xT[(size_t)(j0 + jj) * BSIZE + b] = tile[jj][b];
        }
    }
}

// ------- K1: partial[slot][b][c] = sum_{j in slot} x[b][j] * W[j][c] -------
// No LDS, no barriers. x broadcast via v_readlane from a per-wave VGPR chunk;
// W streamed with an explicit 3-deep float4 prefetch pipeline.
// 256 thr x 4 cols = 1024 cols/block; grid = (16, nslots=32) = 512 blocks.
__global__ __launch_bounds__(TPB1, 2) void k_matmul(
        const float* __restrict__ W, const float* __restrict__ xT,
        float* __restrict__ partial, int jb) {
    const int t = threadIdx.x;
    const int l6 = t & 63;                       // lane within wave
    const int c0 = (blockIdx.x * TPB1 + t) * 4;  // 4 columns per thread
    const int j0 = blockIdx.y * jb;
    const int nch = jb >> 3;                     // 8 j's per chunk

    f32x4 acc[BSIZE];
#pragma unroll
    for (int b = 0; b < BSIZE; ++b) acc[b] = (f32x4)(0.f);

    // per-wave x chunk: lane l holds xT[j0*32 + ch*256 + 4l .. +3]
    const float* xbase = xT + (size_t)j0 * BSIZE + (size_t)l6 * 4;
    f32x4 xv = *(const f32x4*)xbase;

    f32x4 wv[11];
#pragma unroll
    for (int p = 0; p < 3; ++p)  // preload rows j0+0..2 (jb >= 8 always)
        wv[p] = *(const f32x4*)(W + (size_t)(j0 + p) * DIM + c0);

    for (int ch = 0; ch < nch; ++ch) {
        int chn = (ch + 1 < nch) ? (ch + 1) : ch;
        f32x4 xnxt = *(const f32x4*)(xbase + (size_t)chn * 256);
#pragma unroll
        for (int jj = 0; jj < 8; ++jj) {
            // prefetch W row (ch*8 + jj + 3), clamped to last valid row
            int grow = j0 + ch * 8 + jj + 3;
            grow = (grow > DIM - 1) ? (DIM - 1) : grow;
            wv[jj + 3] = *(const f32x4*)(W + (size_t)grow * DIM + c0);
            f32x4 w = wv[jj];
#pragma unroll
            for (int b4 = 0; b4 < 8; ++b4) {
                int ln = jj * 8 + b4;  // compile-time lane index
                float s0 = rdlane(xv.x, ln);
                float s1 = rdlane(xv.y, ln);
                float s2 = rdlane(xv.z, ln);
                float s3 = rdlane(xv.w, ln);
                acc[b4 * 4 + 0].x = fmaf(w.x, s0, acc[b4 * 4 + 0].x);
                acc[b4 * 4 + 0].y = fmaf(w.y, s0, acc[b4 * 4 + 0].y);
                acc[b4 * 4 + 0].z = fmaf(w.z, s0, acc[b4 * 4 + 0].z);
                acc[b4 * 4 + 0].w = fmaf(w.w, s0, acc[b4 * 4 + 0].w);
                acc[b4 * 4 + 1].x = fmaf(w.x, s1, acc[b4 * 4 + 1].x);
                acc[b4 * 4 + 1].y = fmaf(w.y, s1, acc[b4 * 4 + 1].y);
                acc[b4 * 4 + 1].z = fmaf(w.z, s1, acc[b4 * 4 + 1].z);
                acc[b4 * 4 + 1].w = fmaf(w.w, s1, acc[b4 * 4 + 1].w);
                acc[b4 * 4 + 2].x = fmaf(w.x, s2, acc[b4 * 4 + 2].x);
                acc[b4 * 4 + 2].y = fmaf(w.y, s2, acc[b4 * 4 + 2].y);
                acc[b4 * 4 + 2].z = fmaf(w.z, s2, acc[b4 * 4 + 2].z);
                acc[b4 * 4 + 2].w = fmaf(w.w, s2, acc[b4 * 4 + 2].w);
                acc[b4 * 4 + 3].x = fmaf(w.x, s3, acc[b4 * 4 + 3].x);
                acc[b4 * 4 + 3].y = fmaf(w.y, s3, acc[b4 * 4 + 3].y);
                acc[b4 * 4 + 3].z = fmaf(w.z, s3, acc[b4 * 4 + 3].z);
                acc[b4 * 4 + 3].w = fmaf(w.w, s3, acc[b4 * 4 + 3].w);
            }
        }
        wv[0] = wv[8]; wv[1] = wv[9]; wv[2] = wv[10];
        xv = xnxt;
    }

    f32x4* pp = (f32x4*)(partial + (size_t)blockIdx.y * BSIZE * DIM);
    const int c4 = c0 >> 2;
#pragma unroll
    for (int b = 0; b < BSIZE; ++b) pp[(size_t)b * (DIM / 4) + c4] = acc[b];
}

// ------- K2: h0 = sum_slots partial + bias (float4, deterministic order) -------
__global__ __launch_bounds__(256) void k_reduce(const float* __restrict__ partial,
                                                const float* __restrict__ bias,
                                                float* __restrict__ h0, int nslots) {
    int i4 = blockIdx.x * 256 + threadIdx.x;  // over B*DIM/4
    int c4 = i4 & (DIM / 4 - 1);
    const f32x4* p = (const f32x4*)partial;
    f32x4 s = ((const f32x4*)bias)[c4];
    for (int sl = 0; sl < nslots; ++sl)
        s += p[(size_t)sl * (BSIZE * DIM / 4) + i4];
    ((f32x4*)h0)[i4] = s;
}

// ---------------- K3 block-wide reductions (1024 thr = 16 waves) ----------------
__device__ __forceinline__ float block_reduce_max(float v, float* red) {
#pragma unroll
    for (int off = 1; off < 64; off <<= 1) v = fmaxf(v, __shfl_xor(v, off));
    int lane = threadIdx.x & 63, wv = threadIdx.x >> 6;
    if (lane == 0) red[wv] = v;
    __syncthreads();
    if (threadIdx.x == 0) {
        float m = red[0];
#pragma unroll
        for (int w = 1; w < TPB3 / 64; ++w) m = fmaxf(m, red[w]);
        red[0] = m;
    }
    __syncthreads();
    float r = red[0];
    __syncthreads();
    return r;
}

__device__ __forceinline__ float block_reduce_sum(float v, float* red) {
#pragma unroll
    for (int off = 1; off < 64; off <<= 1) v += __shfl_xor(v, off);
    int lane = threadIdx.x & 63, wv = threadIdx.x >> 6;
    if (lane == 0) red[wv] = v;
    __syncthreads();
    if (threadIdx.x == 0) {
        float s = red[0];
#pragma unroll
        for (int w = 1; w < TPB3 / 64; ++w) s += red[w];
        red[0] = s;
    }
    __syncthreads();
    float r = red[0];
    __syncthreads();
    return r;
}

__device__ __forceinline__ int block_argmax(float v, int idx, float* redf, int* redi) {
#pragma unroll
    for (int off = 1; off < 64; off <<= 1) {
        float ov = __shfl_xor(v, off);
        int oi = __shfl_xor(idx, off);
        if (ov > v || (ov == v && oi < idx)) { v = ov; idx = oi; }
    }
    int lane = threadIdx.x & 63, wv = threadIdx.x >> 6;
    if (lane == 0) { redf[wv] = v; redi[wv] = idx; }
    __syncthreads();
    if (threadIdx.x == 0) {
        float bv = redf[0]; int bi = redi[0];
#pragma unroll
        for (int w = 1; w < TPB3 / 64; ++w) {
            float ov = redf[w]; int oi = redi[w];
            if (ov > bv || (ov == bv && oi < bi)) { bv = ov; bi = oi; }
        }
        redi[0] = bi;
    }
    __syncthreads();
    int r = redi[0];
    __syncthreads();
    return r;
}

// ------- K3: per-row sampler, one block per batch row, h/sg in registers -------
__global__ __launch_bounds__(TPB3) void k_sample(
        const float* __restrict__ x, const float* __restrict__ W,
        const float* __restrict__ h0, const float* __restrict__ gumbel,
        const float* __restrict__ au, const int* __restrict__ radius,
        float* __restrict__ out) {
    __shared__ float redf[TPB3 / 64];
    __shared__ int   redi[TPB3 / 64];
    __shared__ float s_delta;
    const int b = blockIdx.x;
    const int t = threadIdx.x;

    const f32x4* h0v = (const f32x4*)(h0 + (size_t)b * DIM);
    const f32x4* xin = (const f32x4*)(x + (size_t)b * DIM);

    f32x4 h[KV], sg[KV];
#pragma unroll
    for (int v = 0; v < KV; ++v) {
        h[v] = h0v[t + v * TPB3];
        f32x4 xx = xin[t + v * TPB3];
        sg[v] = (f32x4)(1.0f) - 2.0f * xx;  // exactly +/-1
    }

    // Zx = logsumexp(sg*h*0.5)
    float lmax = -INFINITY;
#pragma unroll
    for (int v = 0; v < KV; ++v) {
        f32x4 l = sg[v] * h[v] * 0.5f;
        lmax = fmaxf(lmax, fmaxf(fmaxf(l.x, l.y), fmaxf(l.z, l.w)));
    }
    float m = block_reduce_max(lmax, redf);
    float lsum = 0.f;
#pragma unroll
    for (int v = 0; v < KV; ++v) {
        f32x4 l = sg[v] * h[v] * 0.5f;
        lsum += expf(l.x - m) + expf(l.y - m) + expf(l.z - m) + expf(l.w - m);
    }
    float S = block_reduce_sum(lsum, redf);
    float Zx = logf(S) + m;

    const int rad = radius[b];  // in [1, 9]; masked steps are no-ops
    for (int st = 0; st < rad; ++st) {
        const f32x4* g = (const f32x4*)(gumbel + ((size_t)st * BSIZE + b) * DIM);
        float best = -INFINITY; int bidx = 0;
#pragma unroll
        for (int v = 0; v < KV; ++v) {  // ascending c; strict > keeps first max
            f32x4 l = sg[v] * h[v] * 0.5f + g[t + v * TPB3];
            int base = (t + v * TPB3) * 4;
            if (l.x > best) { best = l.x; bidx = base + 0; }
            if (l.y > best) { best = l.y; bidx = base + 1; }
            if (l.z > best) { best = l.z; bidx = base + 2; }
            if (l.w > best) { best = l.w; bidx = base + 3; }
        }
        int idx = block_argmax(best, bidx, redf, redi);
        int c4 = idx >> 2;
        int towner = c4 & (TPB3 - 1);
        int vsel = c4 >> 10;
        int e = idx & 3;
        if (t == towner) {
            float dv = 0.f;
#pragma unroll
            for (int v = 0; v < KV; ++v) {
                if (v == vsel) {
                    f32x4 s4 = sg[v];
                    float d = (e == 0) ? s4.x : (e == 1) ? s4.y : (e == 2) ? s4.z : s4.w;
                    dv = d;
                    if (e == 0) s4.x = -s4.x;
                    else if (e == 1) s4.y = -s4.y;
                    else if (e == 2) s4.z = -s4.z;
                    else s4.w = -s4.w;
                    sg[v] = s4;
                }
            }
            s_delta = dv;  // delta = (1 - 2*x_old)
        }
        __syncthreads();
        float delta = s_delta;
        const f32x4* wr = (const f32x4*)(W + (size_t)idx * DIM);
#pragma unroll
        for (int v = 0; v < KV; ++v) {  // rank-1 update, coalesced float4
            f32x4 w = wr[t + v * TPB3];
            h[v].x = fmaf(delta, w.x, h[v].x);
            h[v].y = fmaf(delta, w.y, h[v].y);
            h[v].z = fmaf(delta, w.z, h[v].z);
            h[v].w = fmaf(delta, w.w, h[v].w);
        }
        __syncthreads();
    }

    // Zy
    lmax = -INFINITY;
#pragma unroll
    for (int v = 0; v < KV; ++v) {
        f32x4 l = sg[v] * h[v] * 0.5f;
        lmax = fmaxf(lmax, fmaxf(fmaxf(l.x, l.y), fmaxf(l.z, l.w)));
    }
    m = block_reduce_max(lmax, redf);
    lsum = 0.f;
#pragma unroll
    for (int v = 0; v < KV; ++v) {
        f32x4 l = sg[v] * h[v] * 0.5f;
        lsum += expf(l.x - m) + expf(l.y - m) + expf(l.z - m) + expf(l.w - m);
    }
    S = block_reduce_sum(lsum, redf);
    float Zy = logf(S) + m;

    int accepted = (expf(Zx - Zy) >= au[b]) ? 1 : 0;
    f32x4* ov = (f32x4*)(out + (size_t)b * DIM);
#pragma unroll
    for (int v = 0; v < KV; ++v) {
        f32x4 y;
        y.x = (sg[v].x < 0.f) ? 1.f : 0.f;
        y.y = (sg[v].y < 0.f) ? 1.f : 0.f;
        y.z = (sg[v].z < 0.f) ? 1.f : 0.f;
        y.w = (sg[v].w < 0.f) ? 1.f : 0.f;
        ov[t + v * TPB3] = accepted ? y : xin[t + v * TPB3];
    }
}

extern "C" void kernel_launch(void* const* d_in, const int* in_sizes, int n_in,
                              void* d_out, int out_size, void* d_ws, size_t ws_size,
                              hipStream_t stream) {
    (void)in_sizes; (void)n_in; (void)out_size;
    const float* x      = (const float*)d_in[0];
    const float* W      = (const float*)d_in[1];
    const float* bias   = (const float*)d_in[2];
    const float* gumbel = (const float*)d_in[3];
    const float* au     = (const float*)d_in[4];
    const int*   radius = (const int*)d_in[5];
    float* out = (float*)d_out;

    // ws layout: xT (2 MB) | partial (nslots * 2 MB) | h0 (2 MB)
    float* xT = (float*)d_ws;
    size_t xt_elems = (size_t)DIM * BSIZE;
    int nslots = 32;  // 16 col-blocks x 32 slots = 512 blocks = 2 blocks/CU
    while (nslots > 1) {
        size_t need = (xt_elems + (size_t)(nslots + 1) * BSIZE * DIM) * sizeof(float);
        if (need <= ws_size) break;
        nslots >>= 1;
    }
    float* partial = xT + xt_elems;
    float* h0 = partial + (size_t)nslots * BSIZE * DIM;

    k_xpose<<<DIM / 64, 256, 0, stream>>>(x, xT);
    dim3 g1(DIM / (TPB1 * 4), nslots);
    k_matmul<<<g1, TPB1, 0, stream>>>(W, xT, partial, DIM / nslots);
    k_reduce<<<(BSIZE * DIM / 4) / 256, 256, 0, stream>>>(partial, bias, h0, nslots);
    k_sample<<<BSIZE, TPB3, 0, stream>>>(x, W, h0, gumbel, au, radius, out);
}